// Round 9
// baseline (225.014 us; speedup 1.0000x reference)
//
#include <hip/hip_runtime.h>
#include <stdint.h>

typedef float f32x4 __attribute__((ext_vector_type(4)));
typedef __bf16 bf16x8 __attribute__((ext_vector_type(8)));
typedef __bf16 bf16x4 __attribute__((ext_vector_type(4)));

#define NROWS 65536     // 16 * 4096 x-rows
#define NCODES 4096
#define NDIM 64
#define NSPLIT 4        // code stripes (cross-block)
#define STEPS 32        // 1024 codes per stripe / 32 codes per step
#define SSTEP 4         // steps per barrier phase
#define PHASES (STEPS / SSTEP)  // 8
#define NRG 256         // row groups (256 rows each)

// ws layout (bytes):
//   [0x000000, 0x080000): codes bf16        4096*64*2 = 512 KB
//   [0x080000, 0x084000): nc2p paired -||c||^2/2: float2[2048]
//       pair index = stripe*512 + step*16 + col ; .x = code col, .y = col+16
//   [0x100000, 0x140000): tarr float[NSPLIT][NROWS]  (stripe-major, 1 MB)
//   [0x200000, 0x240000): marr int  [NSPLIT][NROWS]  (stripe-major, 1 MB)
//   [0x300000, 0x340000): x2   float[NROWS]
//   [0x340000, 0x340400): cnt  int[NRG]  (arrival counters, zeroed by prep)

__device__ __forceinline__ void gld_lds16(const void* g, void* l) {
  __builtin_amdgcn_global_load_lds(
      (const __attribute__((address_space(1))) unsigned int*)g,
      (__attribute__((address_space(3))) unsigned int*)l, 16, 0, 0);
}

// Coalesced prep: 65536 threads, one f32x4 each; 16 lanes per code row.
// Writes bf16 codebook + paired -||c||^2/2 layout; block 0 zeroes cnt[].
__global__ __launch_bounds__(256) void prep_codes_k(const float* __restrict__ codes,
                                                    float* __restrict__ nc2p,
                                                    __bf16* __restrict__ cb,
                                                    int* __restrict__ cnt) {
  const int t = blockIdx.x * 256 + threadIdx.x;  // 0..65535
  if (blockIdx.x == 0) cnt[threadIdx.x] = 0;     // NRG == 256
  f32x4 v = *(const f32x4*)(codes + t * 4);
  bf16x4 o;
  float s = 0.f;
#pragma unroll
  for (int j = 0; j < 4; j++) {
    o[j] = (__bf16)v[j];
    s += v[j] * v[j];
  }
  *(bf16x4*)(cb + t * 4) = o;
  s += __shfl_xor(s, 1);
  s += __shfl_xor(s, 2);
  s += __shfl_xor(s, 4);
  s += __shfl_xor(s, 8);
  if ((threadIdx.x & 15) == 0) {
    const int c = t >> 4;  // code id 0..4095
    const int pidx = (c >> 10) * 512 + ((c >> 5) & 31) * 16 + (c & 15);
    const int half = (c >> 4) & 1;
    nc2p[pidx * 2 + half] = -0.5f * s;
  }
}

// Block = 256 thr = 4 waves sharing ONE 1024-code stripe through LDS; wave w
// owns 64 rows. Phase = 4 steps of 32 codes: stage 16KB once per phase,
// one barrier per phase. nc2 pairs in LDS. Swizzle involution (rule #21):
// LDS[P]=G[P^((P>>7&7)<<4)] on store, reader XORs the same -> identity.
// Block mapping: stripe=bid>>8, rowgrp=bid&255 -> a rowgrp's 4 blocks are
// bids {r,r+256,r+512,r+768}, all same XCD (mod 8) -> partials stay L2-local.
// FUSED FINALIZE: stripe-major partials; last-arriving block of each rowgrp
// (device atomic counter) merges 4 partials and writes out[] directly.
// A-frag (mfma_f32_16x16x32_bf16): lane holds A[m=lane&15][k=quad*8+j].
// C/D: col(n)=lane&15, row(m)=quad*4+reg (m89/m91-verified).
// MFMA C-init = -||c||^2/2 so acc = dot - c2/2; argmax(acc)==argmin d2;
// d2 = x2 - 2*acc (exact *2). Strict '>' + ascending order => lowest index.
__global__ __launch_bounds__(256, 4) void nn_main(const float* __restrict__ x,
                                                  const __bf16* __restrict__ cbv,
                                                  const float2* __restrict__ nc2p,
                                                  float* __restrict__ tarr,
                                                  int* __restrict__ marr,
                                                  float* __restrict__ x2arr,
                                                  int* __restrict__ cnt,
                                                  int* __restrict__ out) {
  const int tid  = threadIdx.x;
  const int lane = tid & 63;
  const int w    = tid >> 6;   // wave id = row chunk
  const int col  = lane & 15;
  const int quad = lane >> 4;
  const int stripe = blockIdx.x >> 8;      // 0..3
  const int rowgrp = blockIdx.x & 255;     // 0..255
  const int rowbase = rowgrp * 256 + w * 64;
  const char* cbb = (const char*)cbv;

  __shared__ __align__(16) char stage[2][SSTEP * 4096];  // 32 KB
  __shared__ __align__(8) float2 ncl[512];               // 4 KB: [step][col]
  __shared__ int lastflag;

  // ---- stage this stripe's nc2 pairs (4 KB) + phase 0 (16 KB) ----
  const uint32_t schunk = ((uint32_t)(tid * 16)) ^ ((((uint32_t)tid >> 3) & 7u) << 4);
  const char* srcbase = cbb + (uint32_t)stripe * 131072u + schunk;
  gld_lds16((const char*)nc2p + stripe * 4096 + tid * 16, (char*)ncl + w * 1024);
#pragma unroll
  for (int i = 0; i < SSTEP; i++)
    gld_lds16(srcbase + i * 4096, &stage[0][i * 4096 + w * 1024]);

  // ---- A fragments (fp32 -> bf16) + ||x||^2 (overlaps with stages) ----
  bf16x8 a[4][2];
  float x2part[4];
#pragma unroll
  for (int rt = 0; rt < 4; rt++) {
    const float* xr = x + (rowbase + rt * 16 + col) * NDIM + quad * 8;
    float p = 0.f;
#pragma unroll
    for (int kc = 0; kc < 2; kc++) {
      f32x4 v0 = *(const f32x4*)(xr + kc * 32);
      f32x4 v1 = *(const f32x4*)(xr + kc * 32 + 4);
      bf16x8 af;
#pragma unroll
      for (int j = 0; j < 4; j++) {
        af[j]     = (__bf16)v0[j];
        af[j + 4] = (__bf16)v1[j];
        p += v0[j] * v0[j] + v1[j] * v1[j];
      }
      a[rt][kc] = af;
    }
    x2part[rt] = p;
  }
#pragma unroll
  for (int rt = 0; rt < 4; rt++) {
    float p = x2part[rt];
    p += __shfl_xor(p, 16);
    p += __shfl_xor(p, 32);
    x2part[rt] = p;
  }
  if (stripe == 0 && quad == 0) {
#pragma unroll
    for (int rt = 0; rt < 4; rt++) x2arr[rowbase + rt * 16 + col] = x2part[rt];
  }

  float bestT[4][4];
  int bestM[4][4];
#pragma unroll
  for (int rt = 0; rt < 4; rt++)
#pragma unroll
    for (int j = 0; j < 4; j++) {
      bestT[rt][j] = -3.0e38f;
      bestM[rt][j] = 0;
    }

  // ---- reader LDS byte offsets (swizzled), within a 4KB tile ----
  const uint32_t swz = ((uint32_t)(col & 7)) << 4;
  const uint32_t o00 = ((uint32_t)(col * 128 + quad * 16)) ^ swz;
  const uint32_t o01 = ((uint32_t)(col * 128 + 64 + quad * 16)) ^ swz;
  const uint32_t o10 = ((uint32_t)(2048 + col * 128 + quad * 16)) ^ swz;
  const uint32_t o11 = ((uint32_t)(2048 + col * 128 + 64 + quad * 16)) ^ swz;

  const int mibase = stripe * 1024 + col;

  __syncthreads();  // ncl + phase 0 staged

#pragma unroll 1
  for (int p = 0; p < PHASES; ++p) {
    // prefetch next phase into the other buffer (in flight across this phase)
    if (p < PHASES - 1) {
      const char* sp = srcbase + (p + 1) * (SSTEP * 4096);
      char* dst = &stage[(p + 1) & 1][w * 1024];
#pragma unroll
      for (int i = 0; i < SSTEP; i++) gld_lds16(sp + i * 4096, dst + i * 4096);
    }
    const char* sb = stage[p & 1];
#pragma unroll
    for (int ss = 0; ss < SSTEP; ss++) {
      const int s = p * SSTEP + ss;  // global step 0..31
      const float2 nv = ncl[s * 16 + col];
      bf16x8 b00 = *(const bf16x8*)(sb + ss * 4096 + o00);
      bf16x8 b01 = *(const bf16x8*)(sb + ss * 4096 + o01);
      bf16x8 b10 = *(const bf16x8*)(sb + ss * 4096 + o10);
      bf16x8 b11 = *(const bf16x8*)(sb + ss * 4096 + o11);
      f32x4 ci0 = {nv.x, nv.x, nv.x, nv.x};
      f32x4 ci1 = {nv.y, nv.y, nv.y, nv.y};
      const int mi0 = mibase + s * 32;
      const int mi1 = mi0 + 16;
#pragma unroll
      for (int rt = 0; rt < 4; rt++) {
        f32x4 acc0 = __builtin_amdgcn_mfma_f32_16x16x32_bf16(a[rt][0], b00, ci0, 0, 0, 0);
        acc0 = __builtin_amdgcn_mfma_f32_16x16x32_bf16(a[rt][1], b01, acc0, 0, 0, 0);
        f32x4 acc1 = __builtin_amdgcn_mfma_f32_16x16x32_bf16(a[rt][0], b10, ci1, 0, 0, 0);
        acc1 = __builtin_amdgcn_mfma_f32_16x16x32_bf16(a[rt][1], b11, acc1, 0, 0, 0);
#pragma unroll
        for (int j = 0; j < 4; j++) {
          if (acc0[j] > bestT[rt][j]) { bestT[rt][j] = acc0[j]; bestM[rt][j] = mi0; }
          if (acc1[j] > bestT[rt][j]) { bestT[rt][j] = acc1[j]; bestM[rt][j] = mi1; }
        }
      }
    }
    __syncthreads();  // next buffer staged; this buffer free
  }

  // ---- butterfly argmax across the 16 lanes sharing each row; write partials
  //      (stripe-major: contiguous full-line stores, no cross-block sharing) ----
#pragma unroll
  for (int rt = 0; rt < 4; rt++) {
#pragma unroll
    for (int j = 0; j < 4; j++) {
      float bt = bestT[rt][j];
      int bm = bestM[rt][j];
#pragma unroll
      for (int off = 1; off < 16; off <<= 1) {
        float ot = __shfl_xor(bt, off);
        int om = __shfl_xor(bm, off);
        if (ot > bt || (ot == bt && om < bm)) {
          bt = ot;
          bm = om;
        }
      }
      if (col == 0) {
        const int row = rowbase + rt * 16 + quad * 4 + j;
        tarr[stripe * NROWS + row] = bt;
        marr[stripe * NROWS + row] = bm;
      }
    }
  }

  // ---- fused finalize: last-arriving block of this rowgrp merges partials ----
  __threadfence();   // release partial stores to device scope
  __syncthreads();
  if (tid == 0) {
    const int old = atomicAdd(&cnt[rowgrp], 1);
    lastflag = (old == NSPLIT - 1);
  }
  __syncthreads();
  if (lastflag) {
    __threadfence();  // acquire side
    const int row = rowgrp * 256 + tid;
    float bt = tarr[row];
    int bm = marr[row];
#pragma unroll
    for (int s = 1; s < NSPLIT; s++) {
      const float tv = tarr[s * NROWS + row];
      const int m = marr[s * NROWS + row];
      if (tv > bt || (tv == bt && m < bm)) {
        bt = tv;
        bm = m;
      }
    }
    const float d2 = fmaf(-2.0f, bt, x2arr[row]);  // min squared distance
    out[row] = (d2 <= 0.1f) ? bm : -1;
  }
}

extern "C" void kernel_launch(void* const* d_in, const int* in_sizes, int n_in,
                              void* d_out, int out_size, void* d_ws, size_t ws_size,
                              hipStream_t stream) {
  const float* x = (const float*)d_in[0];      // [65536][64] fp32
  const float* codes = (const float*)d_in[1];  // [4096][64] fp32
  int* out = (int*)d_out;                      // [65536] int32

  char* ws = (char*)d_ws;
  __bf16* cb = (__bf16*)ws;                     // 512 KB
  float* nc2p = (float*)(ws + 0x080000);        // 16 KB (float2[2048])
  float* tarr = (float*)(ws + 0x100000);        // 1 MB  [NSPLIT][NROWS]
  int* marr = (int*)(ws + 0x200000);            // 1 MB  [NSPLIT][NROWS]
  float* x2arr = (float*)(ws + 0x300000);       // 256 KB
  int* cnt = (int*)(ws + 0x340000);             // 1 KB

  prep_codes_k<<<256, 256, 0, stream>>>(codes, nc2p, cb, cnt);
  nn_main<<<1024, 256, 0, stream>>>(x, cb, (const float2*)nc2p, tarr, marr,
                                    x2arr, cnt, out);
}

// Round 10
// 114.387 us; speedup vs baseline: 1.9671x; 1.9671x over previous
//
#include <hip/hip_runtime.h>
#include <stdint.h>

typedef float f32x4 __attribute__((ext_vector_type(4)));
typedef __bf16 bf16x8 __attribute__((ext_vector_type(8)));
typedef __bf16 bf16x4 __attribute__((ext_vector_type(4)));

#define NROWS 65536     // 16 * 4096 x-rows
#define NCODES 4096
#define NDIM 64
#define NSPLIT 4        // code stripes (cross-block)
#define STEPS 32        // 1024 codes per stripe / 32 codes per step
#define SSTEP 2         // steps per barrier phase
#define PHASES (STEPS / SSTEP)  // 16

// ws layout (bytes):
//   [0x000000, 0x080000): codes bf16        4096*64*2 = 512 KB
//   [0x080000, 0x084000): nc2p paired -||c||^2/2: float2[2048]
//       pair index = stripe*512 + step*16 + col ; .x = code col, .y = col+16
//   [0x100000, 0x140000): tarr float[NSPLIT][NROWS]  (stripe-major, 1 MB)
//   [0x200000, 0x240000): marr int  [NSPLIT][NROWS]  (stripe-major, 1 MB)
//   [0x300000, 0x340000): x2   float[NROWS]

__device__ __forceinline__ void gld_lds16(const void* g, void* l) {
  __builtin_amdgcn_global_load_lds(
      (const __attribute__((address_space(1))) unsigned int*)g,
      (__attribute__((address_space(3))) unsigned int*)l, 16, 0, 0);
}

// Coalesced prep: 65536 threads, one f32x4 each; 16 lanes per code row.
// Writes bf16 codebook + paired -||c||^2/2 layout (see ws map).
__global__ __launch_bounds__(256) void prep_codes_k(const float* __restrict__ codes,
                                                    float* __restrict__ nc2p,
                                                    __bf16* __restrict__ cb) {
  const int t = blockIdx.x * 256 + threadIdx.x;  // 0..65535
  f32x4 v = *(const f32x4*)(codes + t * 4);
  bf16x4 o;
  float s = 0.f;
#pragma unroll
  for (int j = 0; j < 4; j++) {
    o[j] = (__bf16)v[j];
    s += v[j] * v[j];
  }
  *(bf16x4*)(cb + t * 4) = o;
  s += __shfl_xor(s, 1);
  s += __shfl_xor(s, 2);
  s += __shfl_xor(s, 4);
  s += __shfl_xor(s, 8);
  if ((threadIdx.x & 15) == 0) {
    const int c = t >> 4;  // code id 0..4095
    const int pidx = (c >> 10) * 512 + ((c >> 5) & 31) * 16 + (c & 15);
    const int half = (c >> 4) & 1;
    nc2p[pidx * 2 + half] = -0.5f * s;
  }
}

// CLEAN TLP ROUND (r8 redo without spills): 2048 blocks, each wave owns
// 32 rows (rt<2); LDS 20.5KB -> 7 blocks/CU = 28 waves/CU (~1.75x r7).
// launch_bounds(256,6) -> ~85 VGPR budget, state ~55 -> no scratch.
// Block = 4 waves sharing ONE 1024-code stripe via LDS. Phase = 2 steps
// of 32 codes, one barrier per phase. nc2 pairs in LDS.
// Swizzle involution (rule #21): LDS[P]=G[P^((P>>7&7)<<4)] on store, reader
// XORs the same -> identity. Block mapping: stripe=bid>>9, rowgrp=bid&511 ->
// a rowgrp's 4 blocks are {r,r+512,r+1024,r+1536}, same XCD (mod 8).
// NO __threadfence / cross-block handoff in-kernel (r9 lesson: device-scope
// fence forces L2 writeback on non-coherent XCD L2s -> 3x regression).
// A-frag (mfma_f32_16x16x32_bf16): lane holds A[m=lane&15][k=quad*8+j].
// C/D: col(n)=lane&15, row(m)=quad*4+reg (m89/m91-verified).
// MFMA C-init = -||c||^2/2 so acc = dot - c2/2; argmax(acc)==argmin d2;
// d2 = x2 - 2*acc (exact *2). Strict '>' + ascending order => lowest index.
__global__ __launch_bounds__(256, 6) void nn_main(const float* __restrict__ x,
                                                  const __bf16* __restrict__ cbv,
                                                  const float2* __restrict__ nc2p,
                                                  float* __restrict__ tarr,
                                                  int* __restrict__ marr,
                                                  float* __restrict__ x2arr) {
  const int tid  = threadIdx.x;
  const int lane = tid & 63;
  const int w    = tid >> 6;   // wave id = row chunk
  const int col  = lane & 15;
  const int quad = lane >> 4;
  const int stripe = blockIdx.x >> 9;      // 0..3
  const int rowgrp = blockIdx.x & 511;     // 0..511
  const int rowbase = rowgrp * 128 + w * 32;
  const char* cbb = (const char*)cbv;

  __shared__ __align__(16) char stage[2][SSTEP * 4096];  // 16 KB
  __shared__ __align__(8) float2 ncl[512];               // 4 KB: [step][col]

  // ---- stage this stripe's nc2 pairs (4 KB) + phase 0 (8 KB) ----
  const uint32_t schunk = ((uint32_t)(tid * 16)) ^ ((((uint32_t)tid >> 3) & 7u) << 4);
  const char* srcbase = cbb + (uint32_t)stripe * 131072u + schunk;
  gld_lds16((const char*)nc2p + stripe * 4096 + tid * 16, (char*)ncl + w * 1024);
#pragma unroll
  for (int i = 0; i < SSTEP; i++)
    gld_lds16(srcbase + i * 4096, &stage[0][i * 4096 + w * 1024]);

  // ---- A fragments (fp32 -> bf16) + ||x||^2 (overlaps with stages) ----
  bf16x8 a[2][2];
  float x2part[2];
#pragma unroll
  for (int rt = 0; rt < 2; rt++) {
    const float* xr = x + (rowbase + rt * 16 + col) * NDIM + quad * 8;
    float p = 0.f;
#pragma unroll
    for (int kc = 0; kc < 2; kc++) {
      f32x4 v0 = *(const f32x4*)(xr + kc * 32);
      f32x4 v1 = *(const f32x4*)(xr + kc * 32 + 4);
      bf16x8 af;
#pragma unroll
      for (int j = 0; j < 4; j++) {
        af[j]     = (__bf16)v0[j];
        af[j + 4] = (__bf16)v1[j];
        p += v0[j] * v0[j] + v1[j] * v1[j];
      }
      a[rt][kc] = af;
    }
    x2part[rt] = p;
  }
#pragma unroll
  for (int rt = 0; rt < 2; rt++) {
    float p = x2part[rt];
    p += __shfl_xor(p, 16);
    p += __shfl_xor(p, 32);
    x2part[rt] = p;
  }
  if (stripe == 0 && quad == 0) {
#pragma unroll
    for (int rt = 0; rt < 2; rt++) x2arr[rowbase + rt * 16 + col] = x2part[rt];
  }

  float bestT[2][4];
  int bestM[2][4];
#pragma unroll
  for (int rt = 0; rt < 2; rt++)
#pragma unroll
    for (int j = 0; j < 4; j++) {
      bestT[rt][j] = -3.0e38f;
      bestM[rt][j] = 0;
    }

  // ---- reader LDS byte offsets (swizzled), within a 4KB tile ----
  const uint32_t swz = ((uint32_t)(col & 7)) << 4;
  const uint32_t o00 = ((uint32_t)(col * 128 + quad * 16)) ^ swz;
  const uint32_t o01 = ((uint32_t)(col * 128 + 64 + quad * 16)) ^ swz;
  const uint32_t o10 = ((uint32_t)(2048 + col * 128 + quad * 16)) ^ swz;
  const uint32_t o11 = ((uint32_t)(2048 + col * 128 + 64 + quad * 16)) ^ swz;

  const int mibase = stripe * 1024 + col;

  __syncthreads();  // ncl + phase 0 staged

#pragma unroll 1
  for (int p = 0; p < PHASES; ++p) {
    // prefetch next phase into the other buffer (in flight across this phase)
    if (p < PHASES - 1) {
      const char* sp = srcbase + (p + 1) * (SSTEP * 4096);
      char* dst = &stage[(p + 1) & 1][w * 1024];
#pragma unroll
      for (int i = 0; i < SSTEP; i++) gld_lds16(sp + i * 4096, dst + i * 4096);
    }
    const char* sb = stage[p & 1];
#pragma unroll
    for (int ss = 0; ss < SSTEP; ss++) {
      const int s = p * SSTEP + ss;  // global step 0..31
      const float2 nv = ncl[s * 16 + col];
      bf16x8 b00 = *(const bf16x8*)(sb + ss * 4096 + o00);
      bf16x8 b01 = *(const bf16x8*)(sb + ss * 4096 + o01);
      bf16x8 b10 = *(const bf16x8*)(sb + ss * 4096 + o10);
      bf16x8 b11 = *(const bf16x8*)(sb + ss * 4096 + o11);
      f32x4 ci0 = {nv.x, nv.x, nv.x, nv.x};
      f32x4 ci1 = {nv.y, nv.y, nv.y, nv.y};
      const int mi0 = mibase + s * 32;
      const int mi1 = mi0 + 16;
#pragma unroll
      for (int rt = 0; rt < 2; rt++) {
        f32x4 acc0 = __builtin_amdgcn_mfma_f32_16x16x32_bf16(a[rt][0], b00, ci0, 0, 0, 0);
        acc0 = __builtin_amdgcn_mfma_f32_16x16x32_bf16(a[rt][1], b01, acc0, 0, 0, 0);
        f32x4 acc1 = __builtin_amdgcn_mfma_f32_16x16x32_bf16(a[rt][0], b10, ci1, 0, 0, 0);
        acc1 = __builtin_amdgcn_mfma_f32_16x16x32_bf16(a[rt][1], b11, acc1, 0, 0, 0);
#pragma unroll
        for (int j = 0; j < 4; j++) {
          if (acc0[j] > bestT[rt][j]) { bestT[rt][j] = acc0[j]; bestM[rt][j] = mi0; }
          if (acc1[j] > bestT[rt][j]) { bestT[rt][j] = acc1[j]; bestM[rt][j] = mi1; }
        }
      }
    }
    __syncthreads();  // next buffer staged; this buffer free
  }

  // ---- butterfly argmax across the 16 lanes sharing each row; write partials
  //      (stripe-major: contiguous full-line stores, no write amplification) ----
#pragma unroll
  for (int rt = 0; rt < 2; rt++) {
#pragma unroll
    for (int j = 0; j < 4; j++) {
      float bt = bestT[rt][j];
      int bm = bestM[rt][j];
#pragma unroll
      for (int off = 1; off < 16; off <<= 1) {
        float ot = __shfl_xor(bt, off);
        int om = __shfl_xor(bm, off);
        if (ot > bt || (ot == bt && om < bm)) {
          bt = ot;
          bm = om;
        }
      }
      if (col == 0) {
        const int row = rowbase + rt * 16 + quad * 4 + j;
        tarr[stripe * NROWS + row] = bt;
        marr[stripe * NROWS + row] = bm;
      }
    }
  }
}

__global__ __launch_bounds__(256) void nn_final(const float* __restrict__ tarr,
                                                const int* __restrict__ marr,
                                                const float* __restrict__ x2arr,
                                                int* __restrict__ out) {
  const int row = blockIdx.x * blockDim.x + threadIdx.x;
  if (row >= NROWS) return;
  float bt = tarr[row];
  int bm = marr[row];
#pragma unroll
  for (int s = 1; s < NSPLIT; s++) {
    const float t = tarr[s * NROWS + row];
    const int m = marr[s * NROWS + row];
    if (t > bt || (t == bt && m < bm)) {
      bt = t;
      bm = m;
    }
  }
  const float d2 = fmaf(-2.0f, bt, x2arr[row]);  // min squared distance
  out[row] = (d2 <= 0.1f) ? bm : -1;
}

extern "C" void kernel_launch(void* const* d_in, const int* in_sizes, int n_in,
                              void* d_out, int out_size, void* d_ws, size_t ws_size,
                              hipStream_t stream) {
  const float* x = (const float*)d_in[0];      // [65536][64] fp32
  const float* codes = (const float*)d_in[1];  // [4096][64] fp32
  int* out = (int*)d_out;                      // [65536] int32

  char* ws = (char*)d_ws;
  __bf16* cb = (__bf16*)ws;                     // 512 KB
  float* nc2p = (float*)(ws + 0x080000);        // 16 KB (float2[2048])
  float* tarr = (float*)(ws + 0x100000);        // 1 MB  [NSPLIT][NROWS]
  int* marr = (int*)(ws + 0x200000);            // 1 MB  [NSPLIT][NROWS]
  float* x2arr = (float*)(ws + 0x300000);       // 256 KB

  prep_codes_k<<<256, 256, 0, stream>>>(codes, nc2p, cb);
  nn_main<<<2048, 256, 0, stream>>>(x, cb, (const float2*)nc2p, tarr, marr, x2arr);
  nn_final<<<256, 256, 0, stream>>>(tarr, marr, x2arr, out);
}

// Round 11
// 101.619 us; speedup vs baseline: 2.2143x; 1.1256x over previous
//
#include <hip/hip_runtime.h>
#include <stdint.h>

typedef float f32x4 __attribute__((ext_vector_type(4)));
typedef __bf16 bf16x8 __attribute__((ext_vector_type(8)));
typedef __bf16 bf16x4 __attribute__((ext_vector_type(4)));

#define NROWS 65536     // 16 * 4096 x-rows
#define NCODES 4096
#define NDIM 64
#define NSPLIT 4        // code stripes (cross-block)
#define STEPS 32        // 1024 codes per stripe / 32 codes per step
#define SSTEP 2         // steps per barrier phase
#define PHASES (STEPS / SSTEP)  // 16
#define BIAS 2048.0f    // all T' = dot - c^2/2 - BIAS are < 0 (|dot| <= ~120)

// ws layout (bytes):
//   [0x000000, 0x080000): codes bf16        4096*64*2 = 512 KB
//   [0x080000, 0x084000): nc2p paired (-||c||^2/2 - BIAS): float2[2048]
//       pair index = stripe*512 + step*16 + col ; .x = code col, .y = col+16
//   [0x100000, 0x140000): karr u32[NSPLIT][NROWS]  (packed value|code keys, 1 MB)
//   [0x300000, 0x340000): x2   float[NROWS]

__device__ __forceinline__ void gld_lds16(const void* g, void* l) {
  __builtin_amdgcn_global_load_lds(
      (const __attribute__((address_space(1))) unsigned int*)g,
      (__attribute__((address_space(3))) unsigned int*)l, 16, 0, 0);
}

// Coalesced prep: 65536 threads, one f32x4 each; 16 lanes per code row.
// Writes bf16 codebook + paired (-||c||^2/2 - BIAS) layout (see ws map).
__global__ __launch_bounds__(256) void prep_codes_k(const float* __restrict__ codes,
                                                    float* __restrict__ nc2p,
                                                    __bf16* __restrict__ cb) {
  const int t = blockIdx.x * 256 + threadIdx.x;  // 0..65535
  f32x4 v = *(const f32x4*)(codes + t * 4);
  bf16x4 o;
  float s = 0.f;
#pragma unroll
  for (int j = 0; j < 4; j++) {
    o[j] = (__bf16)v[j];
    s += v[j] * v[j];
  }
  *(bf16x4*)(cb + t * 4) = o;
  s += __shfl_xor(s, 1);
  s += __shfl_xor(s, 2);
  s += __shfl_xor(s, 4);
  s += __shfl_xor(s, 8);
  if ((threadIdx.x & 15) == 0) {
    const int c = t >> 4;  // code id 0..4095
    const int pidx = (c >> 10) * 512 + ((c >> 5) & 31) * 16 + (c & 15);
    const int half = (c >> 4) & 1;
    nc2p[pidx * 2 + half] = -0.5f * s - BIAS;
  }
}

// U32-KEY ARGMAX ROUND: MFMA C-init = -c^2/2 - 2048 makes every acc value
// negative, so unsigned bit-pattern order is DESCENDING float order:
// umin(keys) == float-argmax. key = (bits(acc) & ~1023) | (s*32+h*16+col)
// — low 10 bits carry the within-stripe code id; ties resolve to lowest
// code automatically. Per candidate: v_and_or_b32 + v_min_u32 = 2 VALU
// (vs cmp+2*cndmask = 3). 10-bit mantissa truncation costs <=0.25 on T
// (margin on the 0.1 threshold is ~79; below bf16 noise).
// Geometry (r10, best so far): 2048 blocks, 4 waves sharing ONE 1024-code
// stripe via LDS, 32 rows/wave, phase = 2 steps, one barrier per phase.
// Swizzle involution (rule #21): LDS[P]=G[P^((P>>7&7)<<4)] store side,
// reader XORs the same. stripe=bid>>9, rowgrp=bid&511 (XCD-grouped).
// A-frag (mfma_f32_16x16x32_bf16): lane holds A[m=lane&15][k=quad*8+j].
// C/D: col(n)=lane&15, row(m)=quad*4+reg (m89/m91-verified).
__global__ __launch_bounds__(256, 6) void nn_main(const float* __restrict__ x,
                                                  const __bf16* __restrict__ cbv,
                                                  const float2* __restrict__ nc2p,
                                                  uint32_t* __restrict__ karr,
                                                  float* __restrict__ x2arr) {
  const int tid  = threadIdx.x;
  const int lane = tid & 63;
  const int w    = tid >> 6;   // wave id = row chunk
  const int col  = lane & 15;
  const int quad = lane >> 4;
  const int stripe = blockIdx.x >> 9;      // 0..3
  const int rowgrp = blockIdx.x & 511;     // 0..511
  const int rowbase = rowgrp * 128 + w * 32;
  const char* cbb = (const char*)cbv;

  __shared__ __align__(16) char stage[2][SSTEP * 4096];  // 16 KB
  __shared__ __align__(8) float2 ncl[512];               // 4 KB: [step][col]

  // ---- stage this stripe's nc2 pairs (4 KB) + phase 0 (8 KB) ----
  const uint32_t schunk = ((uint32_t)(tid * 16)) ^ ((((uint32_t)tid >> 3) & 7u) << 4);
  const char* srcbase = cbb + (uint32_t)stripe * 131072u + schunk;
  gld_lds16((const char*)nc2p + stripe * 4096 + tid * 16, (char*)ncl + w * 1024);
#pragma unroll
  for (int i = 0; i < SSTEP; i++)
    gld_lds16(srcbase + i * 4096, &stage[0][i * 4096 + w * 1024]);

  // ---- A fragments (fp32 -> bf16) + ||x||^2 (overlaps with stages) ----
  bf16x8 a[2][2];
  float x2part[2];
#pragma unroll
  for (int rt = 0; rt < 2; rt++) {
    const float* xr = x + (rowbase + rt * 16 + col) * NDIM + quad * 8;
    float p = 0.f;
#pragma unroll
    for (int kc = 0; kc < 2; kc++) {
      f32x4 v0 = *(const f32x4*)(xr + kc * 32);
      f32x4 v1 = *(const f32x4*)(xr + kc * 32 + 4);
      bf16x8 af;
#pragma unroll
      for (int j = 0; j < 4; j++) {
        af[j]     = (__bf16)v0[j];
        af[j + 4] = (__bf16)v1[j];
        p += v0[j] * v0[j] + v1[j] * v1[j];
      }
      a[rt][kc] = af;
    }
    x2part[rt] = p;
  }
#pragma unroll
  for (int rt = 0; rt < 2; rt++) {
    float p = x2part[rt];
    p += __shfl_xor(p, 16);
    p += __shfl_xor(p, 32);
    x2part[rt] = p;
  }
  if (stripe == 0 && quad == 0) {
#pragma unroll
    for (int rt = 0; rt < 2; rt++) x2arr[rowbase + rt * 16 + col] = x2part[rt];
  }

  uint32_t bestK[2][4];
#pragma unroll
  for (int rt = 0; rt < 2; rt++)
#pragma unroll
    for (int j = 0; j < 4; j++) bestK[rt][j] = 0xFFFFFFFFu;

  // ---- reader LDS byte offsets (swizzled), within a 4KB tile ----
  const uint32_t swz = ((uint32_t)(col & 7)) << 4;
  const uint32_t o00 = ((uint32_t)(col * 128 + quad * 16)) ^ swz;
  const uint32_t o01 = ((uint32_t)(col * 128 + 64 + quad * 16)) ^ swz;
  const uint32_t o10 = ((uint32_t)(2048 + col * 128 + quad * 16)) ^ swz;
  const uint32_t o11 = ((uint32_t)(2048 + col * 128 + 64 + quad * 16)) ^ swz;

  __syncthreads();  // ncl + phase 0 staged

#pragma unroll 1
  for (int p = 0; p < PHASES; ++p) {
    // prefetch next phase into the other buffer (in flight across this phase)
    if (p < PHASES - 1) {
      const char* sp = srcbase + (p + 1) * (SSTEP * 4096);
      char* dst = &stage[(p + 1) & 1][w * 1024];
#pragma unroll
      for (int i = 0; i < SSTEP; i++) gld_lds16(sp + i * 4096, dst + i * 4096);
    }
    const char* sb = stage[p & 1];
#pragma unroll
    for (int ss = 0; ss < SSTEP; ss++) {
      const int s = p * SSTEP + ss;  // global step 0..31
      const float2 nv = ncl[s * 16 + col];
      bf16x8 b00 = *(const bf16x8*)(sb + ss * 4096 + o00);
      bf16x8 b01 = *(const bf16x8*)(sb + ss * 4096 + o01);
      bf16x8 b10 = *(const bf16x8*)(sb + ss * 4096 + o10);
      bf16x8 b11 = *(const bf16x8*)(sb + ss * 4096 + o11);
      f32x4 ci0 = {nv.x, nv.x, nv.x, nv.x};
      f32x4 ci1 = {nv.y, nv.y, nv.y, nv.y};
      // code-id payloads (low 10 bits of key); sh* uniform -> SALU
      const uint32_t vk0 = (uint32_t)(col | (s * 32));
      const uint32_t vk1 = (uint32_t)(col | (s * 32 + 16));
#pragma unroll
      for (int rt = 0; rt < 2; rt++) {
        f32x4 acc0 = __builtin_amdgcn_mfma_f32_16x16x32_bf16(a[rt][0], b00, ci0, 0, 0, 0);
        acc0 = __builtin_amdgcn_mfma_f32_16x16x32_bf16(a[rt][1], b01, acc0, 0, 0, 0);
        f32x4 acc1 = __builtin_amdgcn_mfma_f32_16x16x32_bf16(a[rt][0], b10, ci1, 0, 0, 0);
        acc1 = __builtin_amdgcn_mfma_f32_16x16x32_bf16(a[rt][1], b11, acc1, 0, 0, 0);
#pragma unroll
        for (int j = 0; j < 4; j++) {
          const uint32_t k0 = (__builtin_bit_cast(uint32_t, acc0[j]) & 0xFFFFFC00u) | vk0;
          if (k0 < bestK[rt][j]) bestK[rt][j] = k0;
          const uint32_t k1 = (__builtin_bit_cast(uint32_t, acc1[j]) & 0xFFFFFC00u) | vk1;
          if (k1 < bestK[rt][j]) bestK[rt][j] = k1;
        }
      }
    }
    __syncthreads();  // next buffer staged; this buffer free
  }

  // ---- butterfly umin across the 16 lanes sharing each row; write key ----
#pragma unroll
  for (int rt = 0; rt < 2; rt++) {
#pragma unroll
    for (int j = 0; j < 4; j++) {
      uint32_t bk = bestK[rt][j];
#pragma unroll
      for (int off = 1; off < 16; off <<= 1) {
        const uint32_t ok = (uint32_t)__shfl_xor((int)bk, off);
        if (ok < bk) bk = ok;
      }
      if (col == 0) {
        const int row = rowbase + rt * 16 + quad * 4 + j;
        karr[stripe * NROWS + row] = bk;
      }
    }
  }
}

__global__ __launch_bounds__(256) void nn_final(const uint32_t* __restrict__ karr,
                                                const float* __restrict__ x2arr,
                                                int* __restrict__ out) {
  const int row = blockIdx.x * blockDim.x + threadIdx.x;
  if (row >= NROWS) return;
  uint32_t best = karr[row];
  int bs = 0;
#pragma unroll
  for (int s = 1; s < NSPLIT; s++) {
    const uint32_t kk = karr[s * NROWS + row];
    if (kk < best) {  // strict < keeps lowest stripe on exact key ties
      best = kk;
      bs = s;
    }
  }
  const float Tp = __builtin_bit_cast(float, best & 0xFFFFFC00u);  // T - BIAS
  const float d2 = fmaf(-2.0f, Tp, x2arr[row]) - 2.0f * BIAS;      // x2 - 2T
  out[row] = (d2 <= 0.1f) ? (bs * 1024 + (int)(best & 1023u)) : -1;
}

extern "C" void kernel_launch(void* const* d_in, const int* in_sizes, int n_in,
                              void* d_out, int out_size, void* d_ws, size_t ws_size,
                              hipStream_t stream) {
  const float* x = (const float*)d_in[0];      // [65536][64] fp32
  const float* codes = (const float*)d_in[1];  // [4096][64] fp32
  int* out = (int*)d_out;                      // [65536] int32

  char* ws = (char*)d_ws;
  __bf16* cb = (__bf16*)ws;                     // 512 KB
  float* nc2p = (float*)(ws + 0x080000);        // 16 KB (float2[2048])
  uint32_t* karr = (uint32_t*)(ws + 0x100000);  // 1 MB [NSPLIT][NROWS]
  float* x2arr = (float*)(ws + 0x300000);       // 256 KB

  prep_codes_k<<<256, 256, 0, stream>>>(codes, nc2p, cb);
  nn_main<<<2048, 256, 0, stream>>>(x, cb, (const float2*)nc2p, karr, x2arr);
  nn_final<<<256, 256, 0, stream>>>(karr, x2arr, out);
}

// Round 12
// 99.263 us; speedup vs baseline: 2.2669x; 1.0237x over previous
//
#include <hip/hip_runtime.h>
#include <stdint.h>

typedef float f32x4 __attribute__((ext_vector_type(4)));
typedef __bf16 bf16x8 __attribute__((ext_vector_type(8)));
typedef __bf16 bf16x4 __attribute__((ext_vector_type(4)));

#define NROWS 65536     // 16 * 4096 x-rows
#define NCODES 4096
#define NDIM 64
#define NSPLIT 4        // code stripes (cross-block)
#define STEPS 32        // 1024 codes per stripe / 32 codes per step
#define SSTEP 2         // steps per barrier phase
#define PHASES (STEPS / SSTEP)  // 16
#define BIAS 2048.0f    // all T' = dot - c^2/2 - BIAS are < 0 (|dot| <= ~120)
#define STRIPE_BYTES 131072u
#define STRIPE_MASK 0x1FFFFu  // wrap within one stripe's 128KB

// ws layout (bytes):
//   [0x000000, 0x080000): codes bf16        4096*64*2 = 512 KB
//   [0x080000, 0x084000): nc2p paired (-||c||^2/2 - BIAS): float2[2048]
//       pair index = stripe*512 + step*16 + col ; .x = code col, .y = col+16
//   [0x100000, 0x140000): karr u32[NSPLIT][NROWS]  (packed value|code keys, 1 MB)
//   [0x300000, 0x340000): x2   float[NROWS]

__device__ __forceinline__ void gld_lds16(const void* g, void* l) {
  __builtin_amdgcn_global_load_lds(
      (const __attribute__((address_space(1))) unsigned int*)g,
      (__attribute__((address_space(3))) unsigned int*)l, 16, 0, 0);
}

__device__ __forceinline__ uint32_t umin2(uint32_t a, uint32_t b) {
  return a < b ? a : b;
}

// Coalesced prep: 65536 threads, one f32x4 each; 16 lanes per code row.
// Writes bf16 codebook + paired (-||c||^2/2 - BIAS) layout (see ws map).
__global__ __launch_bounds__(256) void prep_codes_k(const float* __restrict__ codes,
                                                    float* __restrict__ nc2p,
                                                    __bf16* __restrict__ cb) {
  const int t = blockIdx.x * 256 + threadIdx.x;  // 0..65535
  f32x4 v = *(const f32x4*)(codes + t * 4);
  bf16x4 o;
  float s = 0.f;
#pragma unroll
  for (int j = 0; j < 4; j++) {
    o[j] = (__bf16)v[j];
    s += v[j] * v[j];
  }
  *(bf16x4*)(cb + t * 4) = o;
  s += __shfl_xor(s, 1);
  s += __shfl_xor(s, 2);
  s += __shfl_xor(s, 4);
  s += __shfl_xor(s, 8);
  if ((threadIdx.x & 15) == 0) {
    const int c = t >> 4;  // code id 0..4095
    const int pidx = (c >> 10) * 512 + ((c >> 5) & 31) * 16 + (c & 15);
    const int half = (c >> 4) & 1;
    nc2p[pidx * 2 + half] = -0.5f * s - BIAS;
  }
}

// U32-KEY ARGMAX (r11, verified) + this round: min3-fused merge and
// PHASE ROTATION — block starts its code sweep at step s0 = rowgrp&31
// (staging offsets wrap mod 128KB). Legal: umin over keys is visit-order
// independent (code id lives in the key). Decorrelates the per-phase
// LDS/MFMA bursts across co-resident blocks and spreads the t=0 L2 fetch
// over 32 tiles. Merge: best = min(best, min(k0,k1)) -> v_min3_u32.
// Geometry: 2048 blocks, 4 waves share ONE 1024-code stripe via LDS,
// 32 rows/wave, phase = 2 steps, one barrier per phase. Swizzle involution
// (rule #21): LDS[P]=G[P^((P>>7&7)<<4)] store side, reader XORs the same.
// stripe=bid>>9, rowgrp=bid&511 (XCD-grouped). A-frag: lane holds
// A[m=lane&15][k=quad*8+j]. C/D: col(n)=lane&15, row(m)=quad*4+reg.
// MFMA C-init = -c^2/2-2048 < 0 -> unsigned bit order = descending float
// order; key = (bits&~1023)|code; umin == argmax, lowest-code tie-break.
__global__ __launch_bounds__(256, 6) void nn_main(const float* __restrict__ x,
                                                  const __bf16* __restrict__ cbv,
                                                  const float2* __restrict__ nc2p,
                                                  uint32_t* __restrict__ karr,
                                                  float* __restrict__ x2arr) {
  const int tid  = threadIdx.x;
  const int lane = tid & 63;
  const int w    = tid >> 6;   // wave id = row chunk
  const int col  = lane & 15;
  const int quad = lane >> 4;
  const int stripe = blockIdx.x >> 9;      // 0..3
  const int rowgrp = blockIdx.x & 511;     // 0..511
  const int rowbase = rowgrp * 128 + w * 32;
  const int s0 = rowgrp & 31;              // phase-rotation start step
  const char* cbb = (const char*)cbv;

  __shared__ __align__(16) char stage[2][SSTEP * 4096];  // 16 KB
  __shared__ __align__(8) float2 ncl[512];               // 4 KB: [step][col]

  // ---- stage this stripe's nc2 pairs (4 KB) + rotated phase 0 (8 KB) ----
  const uint32_t schunk = ((uint32_t)(tid * 16)) ^ ((((uint32_t)tid >> 3) & 7u) << 4);
  const char* srcbase = cbb + (uint32_t)stripe * STRIPE_BYTES + schunk;
  const uint32_t rot = (uint32_t)s0 * 4096u;
  gld_lds16((const char*)nc2p + stripe * 4096 + tid * 16, (char*)ncl + w * 1024);
#pragma unroll
  for (int i = 0; i < SSTEP; i++)
    gld_lds16(srcbase + ((rot + i * 4096u) & STRIPE_MASK),
              &stage[0][i * 4096 + w * 1024]);

  // ---- A fragments (fp32 -> bf16) + ||x||^2 (overlaps with stages) ----
  bf16x8 a[2][2];
  float x2part[2];
#pragma unroll
  for (int rt = 0; rt < 2; rt++) {
    const float* xr = x + (rowbase + rt * 16 + col) * NDIM + quad * 8;
    float p = 0.f;
#pragma unroll
    for (int kc = 0; kc < 2; kc++) {
      f32x4 v0 = *(const f32x4*)(xr + kc * 32);
      f32x4 v1 = *(const f32x4*)(xr + kc * 32 + 4);
      bf16x8 af;
#pragma unroll
      for (int j = 0; j < 4; j++) {
        af[j]     = (__bf16)v0[j];
        af[j + 4] = (__bf16)v1[j];
        p += v0[j] * v0[j] + v1[j] * v1[j];
      }
      a[rt][kc] = af;
    }
    x2part[rt] = p;
  }
#pragma unroll
  for (int rt = 0; rt < 2; rt++) {
    float p = x2part[rt];
    p += __shfl_xor(p, 16);
    p += __shfl_xor(p, 32);
    x2part[rt] = p;
  }
  if (stripe == 0 && quad == 0) {
#pragma unroll
    for (int rt = 0; rt < 2; rt++) x2arr[rowbase + rt * 16 + col] = x2part[rt];
  }

  uint32_t bestK[2][4];
#pragma unroll
  for (int rt = 0; rt < 2; rt++)
#pragma unroll
    for (int j = 0; j < 4; j++) bestK[rt][j] = 0xFFFFFFFFu;

  // ---- reader LDS byte offsets (swizzled), within a 4KB tile ----
  const uint32_t swz = ((uint32_t)(col & 7)) << 4;
  const uint32_t o00 = ((uint32_t)(col * 128 + quad * 16)) ^ swz;
  const uint32_t o01 = ((uint32_t)(col * 128 + 64 + quad * 16)) ^ swz;
  const uint32_t o10 = ((uint32_t)(2048 + col * 128 + quad * 16)) ^ swz;
  const uint32_t o11 = ((uint32_t)(2048 + col * 128 + 64 + quad * 16)) ^ swz;

  __syncthreads();  // ncl + phase 0 staged

#pragma unroll 1
  for (int p = 0; p < PHASES; ++p) {
    // prefetch next phase into the other buffer (wrapped rotated offsets)
    if (p < PHASES - 1) {
      const uint32_t pb = rot + (uint32_t)(p + 1) * (SSTEP * 4096u);
      char* dst = &stage[(p + 1) & 1][w * 1024];
#pragma unroll
      for (int i = 0; i < SSTEP; i++)
        gld_lds16(srcbase + ((pb + i * 4096u) & STRIPE_MASK), dst + i * 4096);
    }
    const char* sb = stage[p & 1];
#pragma unroll
    for (int ss = 0; ss < SSTEP; ss++) {
      const int s_eff = (s0 + p * SSTEP + ss) & 31;  // rotated step 0..31
      const float2 nv = ncl[s_eff * 16 + col];
      bf16x8 b00 = *(const bf16x8*)(sb + ss * 4096 + o00);
      bf16x8 b01 = *(const bf16x8*)(sb + ss * 4096 + o01);
      bf16x8 b10 = *(const bf16x8*)(sb + ss * 4096 + o10);
      bf16x8 b11 = *(const bf16x8*)(sb + ss * 4096 + o11);
      f32x4 ci0 = {nv.x, nv.x, nv.x, nv.x};
      f32x4 ci1 = {nv.y, nv.y, nv.y, nv.y};
      // code-id payloads (low 10 bits of key); s_eff*32 uniform -> SALU
      const uint32_t vk0 = (uint32_t)(col | (s_eff << 5));
      const uint32_t vk1 = vk0 | 16u;
#pragma unroll
      for (int rt = 0; rt < 2; rt++) {
        f32x4 acc0 = __builtin_amdgcn_mfma_f32_16x16x32_bf16(a[rt][0], b00, ci0, 0, 0, 0);
        acc0 = __builtin_amdgcn_mfma_f32_16x16x32_bf16(a[rt][1], b01, acc0, 0, 0, 0);
        f32x4 acc1 = __builtin_amdgcn_mfma_f32_16x16x32_bf16(a[rt][0], b10, ci1, 0, 0, 0);
        acc1 = __builtin_amdgcn_mfma_f32_16x16x32_bf16(a[rt][1], b11, acc1, 0, 0, 0);
#pragma unroll
        for (int j = 0; j < 4; j++) {
          const uint32_t k0 = (__builtin_bit_cast(uint32_t, acc0[j]) & 0xFFFFFC00u) | vk0;
          const uint32_t k1 = (__builtin_bit_cast(uint32_t, acc1[j]) & 0xFFFFFC00u) | vk1;
          // min(best, min(k0,k1)) -> v_min3_u32
          bestK[rt][j] = umin2(bestK[rt][j], umin2(k0, k1));
        }
      }
    }
    __syncthreads();  // next buffer staged; this buffer free
  }

  // ---- butterfly umin across the 16 lanes sharing each row; write key ----
#pragma unroll
  for (int rt = 0; rt < 2; rt++) {
#pragma unroll
    for (int j = 0; j < 4; j++) {
      uint32_t bk = bestK[rt][j];
#pragma unroll
      for (int off = 1; off < 16; off <<= 1) {
        const uint32_t ok = (uint32_t)__shfl_xor((int)bk, off);
        bk = umin2(bk, ok);
      }
      if (col == 0) {
        const int row = rowbase + rt * 16 + quad * 4 + j;
        karr[stripe * NROWS + row] = bk;
      }
    }
  }
}

__global__ __launch_bounds__(256) void nn_final(const uint32_t* __restrict__ karr,
                                                const float* __restrict__ x2arr,
                                                int* __restrict__ out) {
  const int row = blockIdx.x * blockDim.x + threadIdx.x;
  if (row >= NROWS) return;
  uint32_t best = karr[row];
  int bs = 0;
#pragma unroll
  for (int s = 1; s < NSPLIT; s++) {
    const uint32_t kk = karr[s * NROWS + row];
    if (kk < best) {  // strict < keeps lowest stripe on exact key ties
      best = kk;
      bs = s;
    }
  }
  const float Tp = __builtin_bit_cast(float, best & 0xFFFFFC00u);  // T - BIAS
  const float d2 = fmaf(-2.0f, Tp, x2arr[row]) - 2.0f * BIAS;      // x2 - 2T
  out[row] = (d2 <= 0.1f) ? (bs * 1024 + (int)(best & 1023u)) : -1;
}

extern "C" void kernel_launch(void* const* d_in, const int* in_sizes, int n_in,
                              void* d_out, int out_size, void* d_ws, size_t ws_size,
                              hipStream_t stream) {
  const float* x = (const float*)d_in[0];      // [65536][64] fp32
  const float* codes = (const float*)d_in[1];  // [4096][64] fp32
  int* out = (int*)d_out;                      // [65536] int32

  char* ws = (char*)d_ws;
  __bf16* cb = (__bf16*)ws;                     // 512 KB
  float* nc2p = (float*)(ws + 0x080000);        // 16 KB (float2[2048])
  uint32_t* karr = (uint32_t*)(ws + 0x100000);  // 1 MB [NSPLIT][NROWS]
  float* x2arr = (float*)(ws + 0x300000);       // 256 KB

  prep_codes_k<<<256, 256, 0, stream>>>(codes, nc2p, cb);
  nn_main<<<2048, 256, 0, stream>>>(x, cb, (const float2*)nc2p, karr, x2arr);
  nn_final<<<256, 256, 0, stream>>>(karr, x2arr, out);
}